// Round 18
// baseline (147.609 us; speedup 1.0000x reference)
//
#include <hip/hip_runtime.h>

// Barrier-free, LDS-free scanline Laplacian-pyramid level (R13 grid config).
// R17 lesson: 24 waves/CU is already the per-wave-throughput limit (more TLP
// = net loss via halo fetch). This round cuts per-iteration issue work:
// lanes 0/63 carry BOTH adjacent halo col-pairs (ha/hb rolling windows), so
// edge down-values and edge tap substitutions are lane-local -- the 7
// broadcast shuffles of R13 vanish; only 5 nearest-neighbor shuffles remain.
// VGPR ~62 under the (256,6) cap (spill canary: WRITE_SIZE inflation).

__device__ __forceinline__ int refl(int t, int n) {
    if (t < 0) t = -t;
    if (t >= n) t = 2 * (n - 1) - t;
    return t;
}

__global__ __launch_bounds__(256, 6) void lap_scan_kernel(
    const float* __restrict__ cur, float* __restrict__ lap,
    float* __restrict__ down, int H, int W, int sh)
{
    const int wid = threadIdx.x >> 6, lane = threadIdx.x & 63;
    const int x0 = blockIdx.x * 128;
    const int y0 = (blockIdx.y * 4 + wid) * sh;
    const int img = blockIdx.z;
    const int Hh = H >> 1, Wh = W >> 1;

    const float* curb = cur + (size_t)img * H * W;
    float* lapb = lap + (size_t)img * H * W;
    float* downb = down + (size_t)img * Hh * Wh;

    const int c0 = x0 + 2 * lane;                 // own col pair (in-image)
    const bool edge = (lane == 0) | (lane == 63);
    // lane0:  haA=(x0-4,x0-3)   haB=(x0-2,x0-1)
    // lane63: haA=(x0+128,129)  haB=(x0+130,131)
    const int baseA = (lane == 0) ? (x0 - 4) : (x0 + 128);
    const int baseB = baseA + 2;
    const bool xb = (x0 == 0) || (x0 + 128 == W);
    const int gA0 = refl(baseA, W), gA1 = refl(baseA + 1, W);
    const int gB0 = refl(baseB, W), gB1 = refl(baseB + 1, W);

    auto loadOwn = [&](int rho) -> float2 {
        return *(const float2*)(curb + (size_t)refl(y0 + rho, H) * W + c0);
    };
    auto loadA = [&](int rho) -> float2 {
        const float* rp = curb + (size_t)refl(y0 + rho, H) * W;
        float2 v;
        if (xb) { v.x = rp[gA0]; v.y = rp[gA1]; }
        else    { v = *(const float2*)(rp + baseA); }
        return v;
    };
    auto loadB = [&](int rho) -> float2 {
        const float* rp = curb + (size_t)refl(y0 + rho, H) * W;
        float2 v;
        if (xb) { v.x = rp[gB0]; v.y = rp[gB1]; }
        else    { v = *(const float2*)(rp + baseB); }
        return v;
    };

    // prologue: window = pixel rows y0-4 .. y0 (iteration a covers 2a-2..2a+2)
    float2 w0 = loadOwn(-4), w1 = loadOwn(-3), w2 = loadOwn(-2),
           w3 = loadOwn(-1), w4 = loadOwn(0);
    float2 a0 = {0,0}, a1 = {0,0}, a2 = {0,0}, a3 = {0,0}, a4 = {0,0};
    float2 b0 = {0,0}, b1 = {0,0}, b2 = {0,0}, b3 = {0,0}, b4 = {0,0};
    if (edge) {
        a0 = loadA(-4); a1 = loadA(-3); a2 = loadA(-2); a3 = loadA(-1); a4 = loadA(0);
        b0 = loadB(-4); b1 = loadB(-3); b2 = loadB(-2); b3 = loadB(-1); b4 = loadB(0);
    }

    float dm2a = 0, dm2b = 0, dm2c = 0, dm1a = 0, dm1b = 0, dm1c = 0;
    const int aEnd = sh >> 1;

    for (int a = -1; a <= aEnd; ++a) {
        // 1. issue next row-pair loads; they land under this iteration's math
        float2 nw3 = {0,0}, nw4 = {0,0};
        float2 na3 = {0,0}, na4 = {0,0}, nb3 = {0,0}, nb4 = {0,0};
        const bool more = (a < aEnd);
        if (more) {
            nw3 = loadOwn(2 * a + 3); nw4 = loadOwn(2 * a + 4);
            if (edge) {
                na3 = loadA(2 * a + 3); na4 = loadA(2 * a + 4);
                nb3 = loadB(2 * a + 3); nb4 = loadB(2 * a + 4);
            }
        }

        // 2. vertical 5-tap (own cols; halo cols on edge lanes only)
        float vE = w0.x + 4.f * w1.x + 6.f * w2.x + 4.f * w3.x + w4.x;
        float vO = w0.y + 4.f * w1.y + 6.f * w2.y + 4.f * w3.y + w4.y;
        float haE = 0, haO = 0, hbE = 0, hbO = 0;
        if (edge) {
            haE = a0.x + 4.f * a1.x + 6.f * a2.x + 4.f * a3.x + a4.x;
            haO = a0.y + 4.f * a1.y + 6.f * a2.y + 4.f * a3.y + a4.y;
            hbE = b0.x + 4.f * b1.x + 6.f * b2.x + 4.f * b3.x + b4.x;
            hbO = b0.y + 4.f * b1.y + 6.f * b2.y + 4.f * b3.y + b4.y;
        }

        // 3. horizontal taps: 3 nearest-neighbor shuffles + local edge subs
        float eL = __shfl_up(vE, 1);    // t(c0-2)
        float oL = __shfl_up(vO, 1);    // t(c0-1)
        float eR = __shfl_down(vE, 1);  // t(c0+2)
        if (lane == 0)  { eL = hbE; oL = hbO; }
        if (lane == 63) { eR = haE; }

        // 4. down value at down col x0/2+lane (row y0/2+a)
        float dv = (eL + 4.f * oL + 6.f * vE + 4.f * vO + eR) * (1.f / 256.f);
        // edge down cols (lane-local, no broadcasts):
        //   lane0:  down col -1, center px x0-2: taps t(x0-4..x0)
        //   lane63: down col 64, center px x0+128: taps t(x0+126..x0+130)
        float dEdge = 0;
        if (lane == 0)
            dEdge = (haE + 4.f * haO + 6.f * hbE + 4.f * hbO + vE) * (1.f / 256.f);
        if (lane == 63)
            dEdge = (vE + 4.f * vO + 6.f * haE + 4.f * haO + hbE) * (1.f / 256.f);

        // 5. neighbor triplet (down cols lane-1, lane, lane+1)
        float da = __shfl_up(dv, 1);
        float dc = __shfl_down(dv, 1);
        if (lane == 0)  da = dEdge;
        if (lane == 63) dc = dEdge;
        float db = dv;

        if (a >= 0 && a < aEnd)
            downb[(size_t)((y0 >> 1) + a) * Wh + (x0 >> 1) + lane] = dv;

        // 6. emit lap rows y0+2a-2 (=w0) and y0+2a-1 (=w1)
        if (a >= 1) {
            float CEa = dm2a + 6.f * dm1a + da;
            float CEb = dm2b + 6.f * dm1b + db;
            float CEc = dm2c + 6.f * dm1c + dc;
            float COa = 4.f * (dm1a + da);
            float COb = 4.f * (dm1b + db);
            float COc = 4.f * (dm1c + dc);
            float2 oe, oo;
            oe.x = w0.x - (CEa + 6.f * CEb + CEc) * (1.f / 64.f);
            oe.y = w0.y - 4.f * (CEb + CEc) * (1.f / 64.f);
            oo.x = w1.x - (COa + 6.f * COb + COc) * (1.f / 64.f);
            oo.y = w1.y - 4.f * (COb + COc) * (1.f / 64.f);
            *(float2*)(lapb + (size_t)(y0 + 2 * a - 2) * W + c0) = oe;
            *(float2*)(lapb + (size_t)(y0 + 2 * a - 1) * W + c0) = oo;
        }

        // 7. shift rolling state
        dm2a = dm1a; dm2b = dm1b; dm2c = dm1c;
        dm1a = da;   dm1b = db;   dm1c = dc;
        w0 = w2; w1 = w3; w2 = w4;
        if (more) { w3 = nw3; w4 = nw4; }
        if (edge) {
            a0 = a2; a1 = a3; a2 = a4;
            b0 = b2; b1 = b3; b2 = b4;
            if (more) { a3 = na3; a4 = na4; b3 = nb3; b4 = nb4; }
        }
    }
}

extern "C" void kernel_launch(void* const* d_in, const int* in_sizes, int n_in,
                              void* d_out, int out_size, void* d_ws, size_t ws_size,
                              hipStream_t stream) {
    const float* img = (const float*)d_in[0];
    float* out = (float*)d_out;

    const long long BC = 8LL * 3;
    const long long n0 = BC * 1024 * 1024;
    const long long n1 = BC * 512 * 512;
    const long long n2 = BC * 256 * 256;

    float* out0 = out;            // lap0
    float* out1 = out0 + n0;      // lap1
    float* out2 = out1 + n1;      // lap2
    float* out3 = out2 + n2;      // down2

    float* ws0 = (float*)d_ws;    // down0
    float* ws1 = ws0 + n1;        // down1

    // R13's proven grid: (W/128 strips, H/(4*sh), 24 images)
    lap_scan_kernel<<<dim3(1024 / 128, 1024 / (4 * 32), (int)BC), 256, 0, stream>>>(
        img, out0, ws0, 1024, 1024, 32);
    lap_scan_kernel<<<dim3(512 / 128, 512 / (4 * 16), (int)BC), 256, 0, stream>>>(
        ws0, out1, ws1, 512, 512, 16);
    lap_scan_kernel<<<dim3(256 / 128, 256 / (4 * 8), (int)BC), 256, 0, stream>>>(
        ws1, out2, out3, 256, 256, 8);
}

// Round 19
// 74.845 us; speedup vs baseline: 1.9722x; 1.9722x over previous
//
#include <hip/hip_runtime.h>

// Barrier-free, LDS-free scanline Laplacian-pyramid level (R13 structure —
// the measured optimum: 128-px strips, float2/lane, 5-row window, depth-1
// prefetch, 24 waves/CU). This round: compile-time H/W/SH (template) +
// block-uniform y-interior fast path (no per-load refl for 94% of blocks).
// Memory pattern byte-identical to R13's 71.8us run; only address-calc and
// loop overhead shrink. R18 lesson: no new per-lane state (spill canary =
// WRITE_SIZE > 123MB).

__device__ __forceinline__ int refl(int t, int n) {
    if (t < 0) t = -t;
    if (t >= n) t = 2 * (n - 1) - t;
    return t;
}

template <int H, int W, int SH, bool YR>
__device__ __forceinline__ void scan_body(
    const float* __restrict__ curb, float* __restrict__ lapb,
    float* __restrict__ downb, int x0, int y0, int lane)
{
    constexpr int Hh = H >> 1, Wh = W >> 1;
    const int c0 = x0 + 2 * lane;                       // own col pair (in-image)
    const bool haloLane = (lane < 2) | (lane >= 62);
    const int hc0 = (lane < 2) ? (x0 - 4 + 2 * lane) : (x0 + 4 + 2 * lane);
    const bool xb = (x0 == 0) || (x0 + 128 == W);
    const int hg0 = refl(hc0, W), hg1 = refl(hc0 + 1, W);

    auto rowAt = [&](int rho) -> const float* {
        const int r = YR ? refl(y0 + rho, H) : (y0 + rho);
        return curb + (size_t)r * W;
    };
    auto loadOwn = [&](int rho) -> float2 {
        return *(const float2*)(rowAt(rho) + c0);
    };
    auto loadHalo = [&](int rho) -> float2 {
        const float* rp = rowAt(rho);
        float2 v;
        if (xb) { v.x = rp[hg0]; v.y = rp[hg1]; }
        else    { v = *(const float2*)(rp + hc0); }
        return v;
    };

    // prologue: window = pixel rows y0-4 .. y0 (iteration a covers 2a-2..2a+2)
    float2 w0 = loadOwn(-4), w1 = loadOwn(-3), w2 = loadOwn(-2),
           w3 = loadOwn(-1), w4 = loadOwn(0);
    float2 h0 = {0,0}, h1 = {0,0}, h2 = {0,0}, h3 = {0,0}, h4 = {0,0};
    if (haloLane) {
        h0 = loadHalo(-4); h1 = loadHalo(-3); h2 = loadHalo(-2);
        h3 = loadHalo(-1); h4 = loadHalo(0);
    }

    float dm2a = 0, dm2b = 0, dm2c = 0, dm1a = 0, dm1b = 0, dm1c = 0;
    constexpr int aEnd = SH >> 1;

    for (int a = -1; a <= aEnd; ++a) {
        // 1. issue next row-pair loads; they land under this iteration's math
        float2 nw3 = {0,0}, nw4 = {0,0}, nh3 = {0,0}, nh4 = {0,0};
        const bool more = (a < aEnd);
        if (more) {
            nw3 = loadOwn(2 * a + 3); nw4 = loadOwn(2 * a + 4);
            if (haloLane) { nh3 = loadHalo(2 * a + 3); nh4 = loadHalo(2 * a + 4); }
        }

        // 2. vertical 5-tap (own + halo cols)
        float vE = w0.x + 4.f * w1.x + 6.f * w2.x + 4.f * w3.x + w4.x;
        float vO = w0.y + 4.f * w1.y + 6.f * w2.y + 4.f * w3.y + w4.y;
        float hE = h0.x + 4.f * h1.x + 6.f * h2.x + 4.f * h3.x + h4.x;
        float hO = h0.y + 4.f * h1.y + 6.f * h2.y + 4.f * h3.y + h4.y;

        // 3. route halo/edge values (all-lane uniform broadcasts)
        float bhE0 = __shfl(hE, 0),  bhO0 = __shfl(hO, 0);
        float bhE1 = __shfl(hE, 1),  bhO1 = __shfl(hO, 1);
        float bhE62 = __shfl(hE, 62), bhO62 = __shfl(hO, 62);
        float bhE63 = __shfl(hE, 63);
        float bvE0 = __shfl(vE, 0);
        float bvE63 = __shfl(vE, 63), bvO63 = __shfl(vO, 63);

        float sE = __shfl_up(vE, 1), sO = __shfl_up(vO, 1);
        float nE = __shfl_down(vE, 1);
        float eL = (lane == 0) ? bhE1 : sE;    // t(c0-2)
        float oL = (lane == 0) ? bhO1 : sO;    // t(c0-1)
        float eR = (lane == 63) ? bhE62 : nE;  // t(c0+2)

        // 4. horizontal 5-tap -> down value at down col x0/2+lane (row y0/2+a)
        float dv = (eL + 4.f * oL + 6.f * vE + 4.f * vO + eR) * (1.f / 256.f);
        float dvm1 = (bhE0 + 4.f * bhO0 + 6.f * bhE1 + 4.f * bhO1 + bvE0) * (1.f / 256.f);
        float dvp64 = (bvE63 + 4.f * bvO63 + 6.f * bhE62 + 4.f * bhO62 + bhE63) * (1.f / 256.f);

        // 5. neighbor triplet (down cols lane-1, lane, lane+1)
        float su = __shfl_up(dv, 1), sd = __shfl_down(dv, 1);
        float da = (lane == 0) ? dvm1 : su;
        float db = dv;
        float dc = (lane == 63) ? dvp64 : sd;

        if (a >= 0 && a < aEnd)
            downb[(size_t)((y0 >> 1) + a) * Wh + (x0 >> 1) + lane] = dv;

        // 6. emit lap rows y0+2a-2 (=w0) and y0+2a-1 (=w1)
        if (a >= 1) {
            float CEa = dm2a + 6.f * dm1a + da;
            float CEb = dm2b + 6.f * dm1b + db;
            float CEc = dm2c + 6.f * dm1c + dc;
            float COa = 4.f * (dm1a + da);
            float COb = 4.f * (dm1b + db);
            float COc = 4.f * (dm1c + dc);
            float2 oe, oo;
            oe.x = w0.x - (CEa + 6.f * CEb + CEc) * (1.f / 64.f);
            oe.y = w0.y - 4.f * (CEb + CEc) * (1.f / 64.f);
            oo.x = w1.x - (COa + 6.f * COb + COc) * (1.f / 64.f);
            oo.y = w1.y - 4.f * (COb + COc) * (1.f / 64.f);
            *(float2*)(lapb + (size_t)(y0 + 2 * a - 2) * W + c0) = oe;
            *(float2*)(lapb + (size_t)(y0 + 2 * a - 1) * W + c0) = oo;
        }

        // 7. shift rolling state
        dm2a = dm1a; dm2b = dm1b; dm2c = dm1c;
        dm1a = da;   dm1b = db;   dm1c = dc;
        w0 = w2; w1 = w3; w2 = w4;
        if (more) { w3 = nw3; w4 = nw4; }
        h0 = h2; h1 = h3; h2 = h4;
        if (more) { h3 = nh3; h4 = nh4; }
    }
}

template <int H, int W, int SH>
__global__ __launch_bounds__(256, 6) void lap_scan_kernel(
    const float* __restrict__ cur, float* __restrict__ lap,
    float* __restrict__ down)
{
    const int wid = threadIdx.x >> 6, lane = threadIdx.x & 63;
    const int x0 = blockIdx.x * 128;
    const int y0 = (blockIdx.y * 4 + wid) * SH;
    const int img = blockIdx.z;

    const float* curb = cur + (size_t)img * H * W;
    float* lapb = lap + (size_t)img * H * W;
    float* downb = down + (size_t)img * (H >> 1) * (W >> 1);

    // rows touched: y0-4 .. y0+SH+2; interior strips skip all row-reflects
    if (y0 >= 4 && y0 + SH + 2 < H)
        scan_body<H, W, SH, false>(curb, lapb, downb, x0, y0, lane);
    else
        scan_body<H, W, SH, true>(curb, lapb, downb, x0, y0, lane);
}

extern "C" void kernel_launch(void* const* d_in, const int* in_sizes, int n_in,
                              void* d_out, int out_size, void* d_ws, size_t ws_size,
                              hipStream_t stream) {
    const float* img = (const float*)d_in[0];
    float* out = (float*)d_out;

    const long long BC = 8LL * 3;
    const long long n0 = BC * 1024 * 1024;
    const long long n1 = BC * 512 * 512;
    const long long n2 = BC * 256 * 256;

    float* out0 = out;            // lap0
    float* out1 = out0 + n0;      // lap1
    float* out2 = out1 + n1;      // lap2
    float* out3 = out2 + n2;      // down2

    float* ws0 = (float*)d_ws;    // down0
    float* ws1 = ws0 + n1;        // down1

    // R13's proven grid: (W/128 strips, H/(4*SH), 24 images)
    lap_scan_kernel<1024, 1024, 32><<<dim3(8, 8, (int)BC), 256, 0, stream>>>(
        img, out0, ws0);
    lap_scan_kernel<512, 512, 16><<<dim3(4, 8, (int)BC), 256, 0, stream>>>(
        ws0, out1, ws1);
    lap_scan_kernel<256, 256, 8><<<dim3(2, 8, (int)BC), 256, 0, stream>>>(
        ws1, out2, out3);
}

// Round 20
// 71.287 us; speedup vs baseline: 2.0706x; 1.0499x over previous
//
#include <hip/hip_runtime.h>

// Barrier-free, LDS-free scanline Laplacian-pyramid level — EXACT R13 kernel
// (71.8us proven; 7 structural variants all regressed). Only change: levels
// 1/2 get 2x grid TLP (sh halved) — their vertical-halo re-reads are
// L3-resident (down0=25MB, down1=6MB << 256MB L3) so extra fetch is ~free,
// unlike level 0 where R17 measured the halo cost exceeding the TLP gain.

__device__ __forceinline__ int refl(int t, int n) {
    if (t < 0) t = -t;
    if (t >= n) t = 2 * (n - 1) - t;
    return t;
}

__global__ __launch_bounds__(256, 6) void lap_scan_kernel(
    const float* __restrict__ cur, float* __restrict__ lap,
    float* __restrict__ down, int H, int W, int sh)
{
    const int wid = threadIdx.x >> 6, lane = threadIdx.x & 63;
    const int x0 = blockIdx.x * 128;
    const int y0 = (blockIdx.y * 4 + wid) * sh;
    const int img = blockIdx.z;
    const int Hh = H >> 1, Wh = W >> 1;

    const float* curb = cur + (size_t)img * H * W;
    float* lapb = lap + (size_t)img * H * W;
    float* downb = down + (size_t)img * Hh * Wh;

    const int c0 = x0 + 2 * lane;                       // own col pair (in-image)
    const bool haloLane = (lane < 2) | (lane >= 62);
    // halo pairs: lane0:(x0-4,-3) lane1:(x0-2,-1) lane62:(x0+128,129) lane63:(x0+130,131)
    const int hc0 = (lane < 2) ? (x0 - 4 + 2 * lane) : (x0 + 4 + 2 * lane);
    const bool xb = (x0 == 0) || (x0 + 128 == W);
    const int hg0 = refl(hc0, W), hg1 = refl(hc0 + 1, W);

    auto loadOwn = [&](int rho) -> float2 {
        return *(const float2*)(curb + (size_t)refl(y0 + rho, H) * W + c0);
    };
    auto loadHalo = [&](int rho) -> float2 {
        const float* rp = curb + (size_t)refl(y0 + rho, H) * W;
        float2 v;
        if (xb) { v.x = rp[hg0]; v.y = rp[hg1]; }
        else    { v = *(const float2*)(rp + hc0); }
        return v;
    };

    // prologue: window = pixel rows y0-4 .. y0 (iteration a covers 2a-2..2a+2)
    float2 w0 = loadOwn(-4), w1 = loadOwn(-3), w2 = loadOwn(-2),
           w3 = loadOwn(-1), w4 = loadOwn(0);
    float2 h0 = {0,0}, h1 = {0,0}, h2 = {0,0}, h3 = {0,0}, h4 = {0,0};
    if (haloLane) {
        h0 = loadHalo(-4); h1 = loadHalo(-3); h2 = loadHalo(-2);
        h3 = loadHalo(-1); h4 = loadHalo(0);
    }

    float dm2a = 0, dm2b = 0, dm2c = 0, dm1a = 0, dm1b = 0, dm1c = 0;
    const int aEnd = sh >> 1;

    for (int a = -1; a <= aEnd; ++a) {
        // 1. issue next row-pair loads; they land under this iteration's math
        float2 nw3 = {0,0}, nw4 = {0,0}, nh3 = {0,0}, nh4 = {0,0};
        const bool more = (a < aEnd);
        if (more) {
            nw3 = loadOwn(2 * a + 3); nw4 = loadOwn(2 * a + 4);
            if (haloLane) { nh3 = loadHalo(2 * a + 3); nh4 = loadHalo(2 * a + 4); }
        }

        // 2. vertical 5-tap (own + halo cols)
        float vE = w0.x + 4.f * w1.x + 6.f * w2.x + 4.f * w3.x + w4.x;
        float vO = w0.y + 4.f * w1.y + 6.f * w2.y + 4.f * w3.y + w4.y;
        float hE = h0.x + 4.f * h1.x + 6.f * h2.x + 4.f * h3.x + h4.x;
        float hO = h0.y + 4.f * h1.y + 6.f * h2.y + 4.f * h3.y + h4.y;

        // 3. route halo/edge values (all-lane uniform broadcasts)
        float bhE0 = __shfl(hE, 0),  bhO0 = __shfl(hO, 0);
        float bhE1 = __shfl(hE, 1),  bhO1 = __shfl(hO, 1);
        float bhE62 = __shfl(hE, 62), bhO62 = __shfl(hO, 62);
        float bhE63 = __shfl(hE, 63);
        float bvE0 = __shfl(vE, 0);
        float bvE63 = __shfl(vE, 63), bvO63 = __shfl(vO, 63);

        float sE = __shfl_up(vE, 1), sO = __shfl_up(vO, 1);
        float nE = __shfl_down(vE, 1);
        float eL = (lane == 0) ? bhE1 : sE;    // t(c0-2)
        float oL = (lane == 0) ? bhO1 : sO;    // t(c0-1)
        float eR = (lane == 63) ? bhE62 : nE;  // t(c0+2)

        // 4. horizontal 5-tap -> down value at down col x0/2+lane (row y0/2+a)
        float dv = (eL + 4.f * oL + 6.f * vE + 4.f * vO + eR) * (1.f / 256.f);
        float dvm1 = (bhE0 + 4.f * bhO0 + 6.f * bhE1 + 4.f * bhO1 + bvE0) * (1.f / 256.f);
        float dvp64 = (bvE63 + 4.f * bvO63 + 6.f * bhE62 + 4.f * bhO62 + bhE63) * (1.f / 256.f);

        // 5. neighbor triplet (down cols lane-1, lane, lane+1)
        float su = __shfl_up(dv, 1), sd = __shfl_down(dv, 1);
        float da = (lane == 0) ? dvm1 : su;
        float db = dv;
        float dc = (lane == 63) ? dvp64 : sd;

        if (a >= 0 && a < aEnd)
            downb[(size_t)((y0 >> 1) + a) * Wh + (x0 >> 1) + lane] = dv;

        // 6. emit lap rows y0+2a-2 (=w0) and y0+2a-1 (=w1)
        if (a >= 1) {
            float CEa = dm2a + 6.f * dm1a + da;
            float CEb = dm2b + 6.f * dm1b + db;
            float CEc = dm2c + 6.f * dm1c + dc;
            float COa = 4.f * (dm1a + da);
            float COb = 4.f * (dm1b + db);
            float COc = 4.f * (dm1c + dc);
            float2 oe, oo;
            oe.x = w0.x - (CEa + 6.f * CEb + CEc) * (1.f / 64.f);
            oe.y = w0.y - 4.f * (CEb + CEc) * (1.f / 64.f);
            oo.x = w1.x - (COa + 6.f * COb + COc) * (1.f / 64.f);
            oo.y = w1.y - 4.f * (COb + COc) * (1.f / 64.f);
            *(float2*)(lapb + (size_t)(y0 + 2 * a - 2) * W + c0) = oe;
            *(float2*)(lapb + (size_t)(y0 + 2 * a - 1) * W + c0) = oo;
        }

        // 7. shift rolling state
        dm2a = dm1a; dm2b = dm1b; dm2c = dm1c;
        dm1a = da;   dm1b = db;   dm1c = dc;
        w0 = w2; w1 = w3; w2 = w4;
        if (more) { w3 = nw3; w4 = nw4; }
        h0 = h2; h1 = h3; h2 = h4;
        if (more) { h3 = nh3; h4 = nh4; }
    }
}

extern "C" void kernel_launch(void* const* d_in, const int* in_sizes, int n_in,
                              void* d_out, int out_size, void* d_ws, size_t ws_size,
                              hipStream_t stream) {
    const float* img = (const float*)d_in[0];
    float* out = (float*)d_out;

    const long long BC = 8LL * 3;
    const long long n0 = BC * 1024 * 1024;
    const long long n1 = BC * 512 * 512;
    const long long n2 = BC * 256 * 256;

    float* out0 = out;            // lap0
    float* out1 = out0 + n0;      // lap1
    float* out2 = out1 + n1;      // lap2
    float* out3 = out2 + n2;      // down2

    float* ws0 = (float*)d_ws;    // down0
    float* ws1 = ws0 + n1;        // down1

    // level 0: R13's proven config (1536 blocks, 24 waves/CU)
    lap_scan_kernel<<<dim3(1024 / 128, 1024 / (4 * 32), (int)BC), 256, 0, stream>>>(
        img, out0, ws0, 1024, 1024, 32);
    // levels 1/2: 2x TLP vs R13 (halo re-reads are L3-resident -> cheap)
    lap_scan_kernel<<<dim3(512 / 128, 512 / (4 * 8), (int)BC), 256, 0, stream>>>(
        ws0, out1, ws1, 512, 512, 8);
    lap_scan_kernel<<<dim3(256 / 128, 256 / (4 * 4), (int)BC), 256, 0, stream>>>(
        ws1, out2, out3, 256, 256, 4);
}